// Round 19
// baseline (101.966 us; speedup 1.0000x reference)
//
#include <hip/hip_runtime.h>
#include <cstdint>
#include <cstddef>

#define NN 8192
#define INF 512
#define OUTF 64
#define ALPHA 0.2f
#define RSTRIDE 36             // LDS acc row stride (pad)

typedef _Float16 half8 __attribute__((ext_vector_type(8)));
typedef float f32x4 __attribute__((ext_vector_type(4)));

static __device__ inline unsigned short f2h(float f) {
    _Float16 h = (_Float16)f;
    return __builtin_bit_cast(unsigned short, h);
}

// ---------------------------------------------------------------------------
// Kernel 1: Wh = x @ W (proven GEMM path, standalone). Emits FP16 Asw
// (MFMA-A-swizzled Wh) and U = exp(.8 s1) f32, e2ph = exp(s2) fp16,
// e2nh = exp(.2 s2) fp16.
// ---------------------------------------------------------------------------
__global__ __launch_bounds__(256) void k1_gemm(
    const float* __restrict__ x, const float* __restrict__ W,
    const float* __restrict__ a, unsigned short* __restrict__ Asw,
    float* __restrict__ U, unsigned short* __restrict__ e2ph,
    unsigned short* __restrict__ e2nh)
{
    const int tid = threadIdx.x;
    const int i0  = blockIdx.x * 16;
    const int w   = __builtin_amdgcn_readfirstlane(tid >> 6);
    const int c   = tid & 63;
    const float* xr = x + (size_t)(i0 + 4 * w) * INF;
    const float* Wc = W + c;
    float acc[4] = {0.f, 0.f, 0.f, 0.f};

    #pragma unroll 4
    for (int kk = 0; kk < 128; ++kk) {
        const float4 x0 = *(const float4*)(xr + 0 * INF + kk * 4);
        const float4 x1 = *(const float4*)(xr + 1 * INF + kk * 4);
        const float4 x2 = *(const float4*)(xr + 2 * INF + kk * 4);
        const float4 x3 = *(const float4*)(xr + 3 * INF + kk * 4);
        const float w0 = Wc[(kk * 4 + 0) * OUTF];
        const float w1 = Wc[(kk * 4 + 1) * OUTF];
        const float w2 = Wc[(kk * 4 + 2) * OUTF];
        const float w3 = Wc[(kk * 4 + 3) * OUTF];
        acc[0] = fmaf(x0.x, w0, fmaf(x0.y, w1, fmaf(x0.z, w2, fmaf(x0.w, w3, acc[0]))));
        acc[1] = fmaf(x1.x, w0, fmaf(x1.y, w1, fmaf(x1.z, w2, fmaf(x1.w, w3, acc[1]))));
        acc[2] = fmaf(x2.x, w0, fmaf(x2.y, w1, fmaf(x2.z, w2, fmaf(x2.w, w3, acc[2]))));
        acc[3] = fmaf(x3.x, w0, fmaf(x3.y, w1, fmaf(x3.z, w2, fmaf(x3.w, w3, acc[3]))));
    }

    const float a1c = a[c];
    const float a2c = a[64 + c];
    #pragma unroll
    for (int q = 0; q < 4; ++q) {
        float v1 = acc[q] * a1c;
        float v2 = acc[q] * a2c;
        #pragma unroll
        for (int m = 32; m; m >>= 1) {
            v1 += __shfl_xor(v1, m, 64);
            v2 += __shfl_xor(v2, m, 64);
        }
        if (c == 0) {
            const int i = i0 + 4 * w + q;
            U[i]    = __expf((1.0f - ALPHA) * v1);
            e2ph[i] = f2h(__expf(v2));
            e2nh[i] = f2h(__expf(ALPHA * v2));
        }
    }

    const int i   = i0 + 4 * w;
    const int jt  = i >> 5;
    const int sub = (i >> 3) & 3;
    const int e0  = i & 7;
    ushort4 pk;
    pk.x = f2h(acc[0]); pk.y = f2h(acc[1]);
    pk.z = f2h(acc[2]); pk.w = f2h(acc[3]);
    *(ushort4*)&Asw[((size_t)(c >> 4) * 256 + jt) * 512 + ((c & 15) + 16 * sub) * 8 + e0] = pk;
}

// ---------------------------------------------------------------------------
// Kernel 2 (STREAM-FUSED): block = 1024 threads = 16 waves owns a full 32-row
// i-tile; adj is read ONCE, inside this kernel, 512-col supersteps:
//   [issue ss+1 loads (16 dword/thread, 64 B/lane in flight)]
//   [compute superstep ss: wave w -> window ss*512 + w*32, round-18 body]
//   [ballot ss+1 vals -> mask bits in double-buffered LDS]  [barrier]
// No global mask intermediate; loads hide under compute (T14). Epilogue =
// round-18-verified block reduce + direct normalized output.
// ---------------------------------------------------------------------------
__global__ __launch_bounds__(1024) void k2_stream(
    const int* __restrict__ adj, const unsigned short* __restrict__ Asw,
    const float* __restrict__ Ug, const unsigned short* __restrict__ e2ph,
    const unsigned short* __restrict__ e2nh,
    float* __restrict__ out)
{
    __shared__ unsigned lm[2][32][18];          // mask words, dbuf, padded (4.5 KB)
    __shared__ float red[16 * 64 * RSTRIDE];    // 144 KB acc partials
    __shared__ float redl[16 * 32];             // 2 KB rowsum partials

    const int tid = threadIdx.x;
    const int l   = tid & 63;
    const int w   = tid >> 6;                   // 0..15
    const int i0  = blockIdx.x * 32;

    const int il  = l & 15;
    const int kg  = l >> 4;
    const int kg8 = kg * 8;

    const unsigned ua2 = (unsigned)f2h(Ug[i0 + il])      * 0x00010001u;
    const unsigned ub2 = (unsigned)f2h(Ug[i0 + 16 + il]) * 0x00010001u;

    f32x4 a00 = {0,0,0,0}, a01 = {0,0,0,0}, a10 = {0,0,0,0}, a11 = {0,0,0,0};
    f32x4 a20 = {0,0,0,0}, a21 = {0,0,0,0}, a30 = {0,0,0,0}, a31 = {0,0,0,0};
    f32x4 sA  = {0,0,0,0}, sB  = {0,0,0,0};

    half8 ONESH;
    #pragma unroll
    for (int e = 0; e < 8; ++e) ONESH[e] = (_Float16)1.0f;

    int vals[16];

    // wave-load k: idx = w*16+k -> row = idx>>3, chunk = idx&7 (64 cols)
#define LOADS(SS) do {                                                        \
    _Pragma("unroll")                                                         \
    for (int k = 0; k < 16; ++k) {                                            \
        const int idx = w * 16 + k;                                           \
        vals[k] = adj[(size_t)(i0 + (idx >> 3)) * NN + (SS) * 512             \
                      + (idx & 7) * 64 + l];                                  \
    }                                                                         \
} while (0)

#define BALLOT_WRITE(SS) do {                                                 \
    _Pragma("unroll")                                                         \
    for (int k = 0; k < 16; ++k) {                                            \
        const int idx = w * 16 + k;                                           \
        const unsigned long long b = __ballot(vals[k] != 0);                  \
        if (l == 0)                                                           \
            *(unsigned long long*)&lm[(SS) & 1][idx >> 3][(idx & 7) * 2] = b; \
    }                                                                         \
} while (0)

#define SPAIR(DST, U2, EPW, ENW, BITS, R) do {                                \
    unsigned mu_, mx_;                                                        \
    asm("v_pk_mul_f16 %0, %1, %2" : "=v"(mu_) : "v"(U2), "v"(EPW));           \
    asm("v_pk_max_f16 %0, %1, %2" : "=v"(mx_) : "v"(mu_), "v"(ENW));          \
    const int lo_ = (int)((BITS) << (31 - 2 * (R))) >> 31;                    \
    const int hi_ = (int)((BITS) << (30 - 2 * (R))) >> 31;                    \
    DST = mx_ & (((unsigned)hi_ & 0xFFFF0000u) | ((unsigned)lo_ & 0x0000FFFFu)); \
} while (0)

    // prologue: superstep 0 mask bits
    LOADS(0);
    BALLOT_WRITE(0);
    __syncthreads();

    for (int ss = 0; ss < 16; ++ss) {
        if (ss < 15) LOADS(ss + 1);            // in flight during compute

        // ---- compute superstep ss: wave w -> j-window ss*512 + w*32 ----
        const int jw = ss * 512 + w * 32;
        const int jb = ss * 16 + w;            // Asw tile index 0..255

        const unsigned short* Ac = Asw + (size_t)jb * 512 + l * 8;
        half8 A0c = *(const half8*)(Ac);
        half8 A1c = *(const half8*)(Ac + 131072);
        half8 A2c = *(const half8*)(Ac + 262144);
        half8 A3c = *(const half8*)(Ac + 393216);

        uint4 epc = *(const uint4*)(e2ph + jw + kg8);
        uint4 enc = *(const uint4*)(e2nh + jw + kg8);

        const unsigned bAc = (lm[ss & 1][il][w]      >> kg8) & 0xffu;
        const unsigned bBc = (lm[ss & 1][il + 16][w] >> kg8) & 0xffu;

        uint4 wa, wb;
        SPAIR(wa.x, ua2, epc.x, enc.x, bAc, 0);
        SPAIR(wa.y, ua2, epc.y, enc.y, bAc, 1);
        SPAIR(wa.z, ua2, epc.z, enc.z, bAc, 2);
        SPAIR(wa.w, ua2, epc.w, enc.w, bAc, 3);
        SPAIR(wb.x, ub2, epc.x, enc.x, bBc, 0);
        SPAIR(wb.y, ub2, epc.y, enc.y, bBc, 1);
        SPAIR(wb.z, ub2, epc.z, enc.z, bBc, 2);
        SPAIR(wb.w, ub2, epc.w, enc.w, bBc, 3);
        const half8 BA = __builtin_bit_cast(half8, wa);
        const half8 BB = __builtin_bit_cast(half8, wb);

        sA = __builtin_amdgcn_mfma_f32_16x16x32_f16(ONESH, BA, sA, 0, 0, 0);
        sB = __builtin_amdgcn_mfma_f32_16x16x32_f16(ONESH, BB, sB, 0, 0, 0);

        a00 = __builtin_amdgcn_mfma_f32_16x16x32_f16(A0c, BA, a00, 0, 0, 0);
        a01 = __builtin_amdgcn_mfma_f32_16x16x32_f16(A0c, BB, a01, 0, 0, 0);
        a10 = __builtin_amdgcn_mfma_f32_16x16x32_f16(A1c, BA, a10, 0, 0, 0);
        a11 = __builtin_amdgcn_mfma_f32_16x16x32_f16(A1c, BB, a11, 0, 0, 0);
        a20 = __builtin_amdgcn_mfma_f32_16x16x32_f16(A2c, BA, a20, 0, 0, 0);
        a21 = __builtin_amdgcn_mfma_f32_16x16x32_f16(A2c, BB, a21, 0, 0, 0);
        a30 = __builtin_amdgcn_mfma_f32_16x16x32_f16(A3c, BA, a30, 0, 0, 0);
        a31 = __builtin_amdgcn_mfma_f32_16x16x32_f16(A3c, BB, a31, 0, 0, 0);

        if (ss < 15) BALLOT_WRITE(ss + 1);     // waits on vals; other buffer
        __syncthreads();                       // publish lm for ss+1
    }
#undef SPAIR
#undef BALLOT_WRITE
#undef LOADS

    // ---- merged epilogue (round-18 verified): block-wide reduce ----
    float* rw = red + (size_t)(w * 64 + l) * RSTRIDE;
    *(float4*)(rw + 0)  = *(float4*)&a00;
    *(float4*)(rw + 4)  = *(float4*)&a01;
    *(float4*)(rw + 8)  = *(float4*)&a10;
    *(float4*)(rw + 12) = *(float4*)&a11;
    *(float4*)(rw + 16) = *(float4*)&a20;
    *(float4*)(rw + 20) = *(float4*)&a21;
    *(float4*)(rw + 24) = *(float4*)&a30;
    *(float4*)(rw + 28) = *(float4*)&a31;
    if (l < 16) {
        redl[w * 32 + il]      = sA[0];
        redl[w * 32 + 16 + il] = sB[0];
    }
    __syncthreads();

    const int row = tid >> 5;            // 0..31
    const int n0  = (tid & 31) * 2;      // 0,2,...,62
    const int h   = row >> 4;
    const int il2 = row & 15;

    float den = 0.f;
    #pragma unroll
    for (int w2 = 0; w2 < 16; ++w2) den += redl[w2 * 32 + row];
    const float inv = 1.0f / den;

    float o2[2];
    #pragma unroll
    for (int e = 0; e < 2; ++e) {
        const int n   = n0 + e;
        const int q   = n >> 4;
        const int kg2 = (n >> 2) & 3;
        const int r   = n & 3;
        float s = 0.f;
        #pragma unroll
        for (int w2 = 0; w2 < 16; ++w2)
            s += red[(size_t)(w2 * 64 + kg2 * 16 + il2) * RSTRIDE + q * 8 + h * 4 + r];
        o2[e] = s * inv;
    }
    *(float2*)&out[(size_t)(i0 + row) * OUTF + n0] = *(float2*)o2;
}

extern "C" void kernel_launch(void* const* d_in, const int* in_sizes, int n_in,
                              void* d_out, int out_size, void* d_ws, size_t ws_size,
                              hipStream_t stream) {
    const float* x   = (const float*)d_in[0];
    const int*   adj = (const int*)d_in[1];
    const float* W   = (const float*)d_in[2];
    const float* a   = (const float*)d_in[3];
    float* out = (float*)d_out;

    char* ws = (char*)d_ws;
    unsigned short* Asw = (unsigned short*)ws;                        // 1 MB
    float* U     = (float*)(ws + (1 << 20));                          // 32 KB
    unsigned short* e2ph = (unsigned short*)(ws + (1 << 20) + 32768); // 16 KB
    unsigned short* e2nh = (unsigned short*)(ws + (1 << 20) + 49152); // 16 KB

    k1_gemm<<<512, 256, 0, stream>>>(x, W, a, Asw, U, e2ph, e2nh);
    k2_stream<<<NN / 32, 1024, 0, stream>>>(adj, Asw, U, e2ph, e2nh, out);
}

// Round 20
// 74.365 us; speedup vs baseline: 1.3712x; 1.3712x over previous
//
#include <hip/hip_runtime.h>
#include <cstdint>
#include <cstddef>

#define NN 8192
#define INF 512
#define OUTF 64
#define ALPHA 0.2f
#define JSPLIT 512             // j-chunk per wave (16 waves cover 8192)
#define NW32 (NN / 32)         // 256
#define GEMM_BLOCKS 512
#define RSTRIDE 36             // LDS acc row stride (pad)

typedef _Float16 half8 __attribute__((ext_vector_type(8)));
typedef float f32x4 __attribute__((ext_vector_type(4)));

static __device__ inline unsigned short f2h(float f) {
    _Float16 h = (_Float16)f;
    return __builtin_bit_cast(unsigned short, h);
}

// ---------------------------------------------------------------------------
// Kernel 01 (fused, GEMM-FIRST — round-18 proven): blocks 0..511 = GEMM
// (start at t=0, ~17us, hidden under the 45us mask stream); blocks 512..8703
// = adj->bitmask pack (276 MB at 6.1 TB/s = 97% of streaming ceiling).
// Epilogue emits FP16 Asw/E2 (U stays f32).
// ---------------------------------------------------------------------------
__global__ __launch_bounds__(256) void k01_fused(
    const float* __restrict__ x, const int* __restrict__ adj,
    const float* __restrict__ W, const float* __restrict__ a,
    unsigned short* __restrict__ Asw, float* __restrict__ U,
    unsigned short* __restrict__ e2ph, unsigned short* __restrict__ e2nh,
    unsigned* __restrict__ mask)
{
    __shared__ int ldsbuf[8192];   // 32 KB (mask path only)
    const int tid = threadIdx.x;

    if (blockIdx.x >= GEMM_BLOCKS) {
        // ---------------- mask path: one adj row ----------------
        const int row = blockIdx.x - GEMM_BLOCKS;
        const int* arow = adj + (size_t)row * NN;

        #pragma unroll
        for (int k = 0; k < 8; ++k) {
            const int i = k * 1024 + tid * 4;
            int4 v = *(const int4*)(arow + i);
            const int p = i ^ (((i >> 7) & 7) << 2);
            *(int4*)&ldsbuf[p] = v;
        }
        __syncthreads();

        unsigned m = 0;
        #pragma unroll
        for (int k = 0; k < 8; ++k) {
            const int i2 = tid * 32 + k * 4;
            const int p2 = i2 ^ (((i2 >> 7) & 7) << 2);
            int4 v = *(const int4*)&ldsbuf[p2];
            m |= (v.x != 0 ? 1u : 0u) << (4 * k);
            m |= (v.y != 0 ? 1u : 0u) << (4 * k + 1);
            m |= (v.z != 0 ? 1u : 0u) << (4 * k + 2);
            m |= (v.w != 0 ? 1u : 0u) << (4 * k + 3);
        }
        mask[(size_t)row * NW32 + tid] = m;
        return;
    }

    // ---------------- GEMM path: 16 rows of Wh per block ----------------
    const int i0 = blockIdx.x * 16;
    const int w  = __builtin_amdgcn_readfirstlane(tid >> 6);
    const int c  = tid & 63;
    const float* xr = x + (size_t)(i0 + 4 * w) * INF;
    const float* Wc = W + c;
    float acc[4] = {0.f, 0.f, 0.f, 0.f};

    #pragma unroll 4
    for (int kk = 0; kk < 128; ++kk) {
        const float4 x0 = *(const float4*)(xr + 0 * INF + kk * 4);
        const float4 x1 = *(const float4*)(xr + 1 * INF + kk * 4);
        const float4 x2 = *(const float4*)(xr + 2 * INF + kk * 4);
        const float4 x3 = *(const float4*)(xr + 3 * INF + kk * 4);
        const float w0 = Wc[(kk * 4 + 0) * OUTF];
        const float w1 = Wc[(kk * 4 + 1) * OUTF];
        const float w2 = Wc[(kk * 4 + 2) * OUTF];
        const float w3 = Wc[(kk * 4 + 3) * OUTF];
        acc[0] = fmaf(x0.x, w0, fmaf(x0.y, w1, fmaf(x0.z, w2, fmaf(x0.w, w3, acc[0]))));
        acc[1] = fmaf(x1.x, w0, fmaf(x1.y, w1, fmaf(x1.z, w2, fmaf(x1.w, w3, acc[1]))));
        acc[2] = fmaf(x2.x, w0, fmaf(x2.y, w1, fmaf(x2.z, w2, fmaf(x2.w, w3, acc[2]))));
        acc[3] = fmaf(x3.x, w0, fmaf(x3.y, w1, fmaf(x3.z, w2, fmaf(x3.w, w3, acc[3]))));
    }

    const float a1c = a[c];
    const float a2c = a[64 + c];
    #pragma unroll
    for (int q = 0; q < 4; ++q) {
        float v1 = acc[q] * a1c;
        float v2 = acc[q] * a2c;
        #pragma unroll
        for (int m = 32; m; m >>= 1) {
            v1 += __shfl_xor(v1, m, 64);
            v2 += __shfl_xor(v2, m, 64);
        }
        if (c == 0) {
            const int i = i0 + 4 * w + q;
            U[i]    = __expf((1.0f - ALPHA) * v1);   // exp(0.8 s1), f32
            e2ph[i] = f2h(__expf(v2));               // exp(s2), fp16
            e2nh[i] = f2h(__expf(ALPHA * v2));       // exp(0.2 s2), fp16
        }
    }

    const int i   = i0 + 4 * w;
    const int jt  = i >> 5;
    const int sub = (i >> 3) & 3;
    const int e0  = i & 7;
    ushort4 pk;
    pk.x = f2h(acc[0]); pk.y = f2h(acc[1]);
    pk.z = f2h(acc[2]); pk.w = f2h(acc[3]);
    *(ushort4*)&Asw[((size_t)(c >> 4) * 256 + jt) * 512 + ((c & 15) + 16 * sub) * 8 + e0] = pk;
}

// ---------------------------------------------------------------------------
// Kernel 2 (MERGED k2+k3, round-18 verified): block = 1024 threads = 16
// waves owns a full 32-row i-tile; wave w owns j-chunk [w*512, w*512+512).
// Round-17 packed-fp16 inner body. NEW this round: s_setprio(1)/(0) around
// the MFMA cluster (T5 — waves here are barrier-free and independently
// phased, the regime where setprio measured +4-7%).
// Epilogue: block-wide LDS reduce, direct normalized output.
// ---------------------------------------------------------------------------
__global__ __launch_bounds__(1024, 4) void k2_final(
    const unsigned* __restrict__ mask, const unsigned short* __restrict__ Asw,
    const float* __restrict__ Ug, const unsigned short* __restrict__ e2ph,
    const unsigned short* __restrict__ e2nh,
    float* __restrict__ out)
{
    __shared__ float red[16 * 64 * RSTRIDE];   // 144 KB acc partials
    __shared__ float redl[16 * 32];            // 2 KB rowsum partials

    const int tid   = threadIdx.x;
    const int l     = tid & 63;
    const int w     = tid >> 6;                // 0..15 = j-chunk
    const int i0    = blockIdx.x * 32;
    const int jbase = w * JSPLIT;
    const int jb32  = jbase >> 5;

    const int il  = l & 15;
    const int kg  = l >> 4;
    const int kg8 = kg * 8;

    const unsigned uaw = f2h(Ug[i0 + il]);
    const unsigned ubw = f2h(Ug[i0 + 16 + il]);
    const unsigned ua2 = uaw * 0x00010001u;
    const unsigned ub2 = ubw * 0x00010001u;

    const unsigned* mbase = mask + (size_t)(i0 + il) * NW32 + jb32 + kg;
    unsigned mA[4], mB[4];
    #pragma unroll
    for (int ss = 0; ss < 4; ++ss) {
        mA[ss] = mbase[ss * 4];
        mB[ss] = mbase[(size_t)16 * NW32 + ss * 4];
    }

    f32x4 a00 = {0,0,0,0}, a01 = {0,0,0,0}, a10 = {0,0,0,0}, a11 = {0,0,0,0};
    f32x4 a20 = {0,0,0,0}, a21 = {0,0,0,0}, a30 = {0,0,0,0}, a31 = {0,0,0,0};
    f32x4 sA  = {0,0,0,0}, sB  = {0,0,0,0};

    half8 ONESH;
    #pragma unroll
    for (int e = 0; e < 8; ++e) ONESH[e] = (_Float16)1.0f;

    uint4 epc = *(const uint4*)(e2ph + jbase + kg8);
    uint4 enc = *(const uint4*)(e2nh + jbase + kg8);
    unsigned bAc = (__shfl(mA[0], il, 64) >> kg8) & 0xffu;
    unsigned bBc = (__shfl(mB[0], il, 64) >> kg8) & 0xffu;

#define SPAIR(DST, U2, EPW, ENW, BITS, R) do {                                \
    unsigned mu_, mx_;                                                        \
    asm("v_pk_mul_f16 %0, %1, %2" : "=v"(mu_) : "v"(U2), "v"(EPW));           \
    asm("v_pk_max_f16 %0, %1, %2" : "=v"(mx_) : "v"(mu_), "v"(ENW));          \
    const int lo_ = (int)((BITS) << (31 - 2 * (R))) >> 31;                    \
    const int hi_ = (int)((BITS) << (30 - 2 * (R))) >> 31;                    \
    DST = mx_ & (((unsigned)hi_ & 0xFFFF0000u) | ((unsigned)lo_ & 0x0000FFFFu)); \
} while (0)

    #pragma unroll
    for (int t = 0; t < 16; ++t) {
        const unsigned short* Ac = Asw + (size_t)(jb32 + t) * 512 + l * 8;
        half8 A0c = *(const half8*)(Ac);
        half8 A1c = *(const half8*)(Ac + 131072);
        half8 A2c = *(const half8*)(Ac + 262144);
        half8 A3c = *(const half8*)(Ac + 393216);

        const int tn = (t < 15) ? t + 1 : t;
        uint4 epn = *(const uint4*)(e2ph + jbase + tn * 32 + kg8);
        uint4 enn = *(const uint4*)(e2nh + jbase + tn * 32 + kg8);
        const int ssn = tn >> 2, ksn = tn & 3;
        unsigned bAn = (__shfl(mA[ssn], il + 16 * ksn, 64) >> kg8) & 0xffu;
        unsigned bBn = (__shfl(mB[ssn], il + 16 * ksn, 64) >> kg8) & 0xffu;

        uint4 wa, wb;
        SPAIR(wa.x, ua2, epc.x, enc.x, bAc, 0);
        SPAIR(wa.y, ua2, epc.y, enc.y, bAc, 1);
        SPAIR(wa.z, ua2, epc.z, enc.z, bAc, 2);
        SPAIR(wa.w, ua2, epc.w, enc.w, bAc, 3);
        SPAIR(wb.x, ub2, epc.x, enc.x, bBc, 0);
        SPAIR(wb.y, ub2, epc.y, enc.y, bBc, 1);
        SPAIR(wb.z, ub2, epc.z, enc.z, bBc, 2);
        SPAIR(wb.w, ub2, epc.w, enc.w, bBc, 3);
        const half8 BA = __builtin_bit_cast(half8, wa);
        const half8 BB = __builtin_bit_cast(half8, wb);

        __builtin_amdgcn_s_setprio(1);
        sA = __builtin_amdgcn_mfma_f32_16x16x32_f16(ONESH, BA, sA, 0, 0, 0);
        sB = __builtin_amdgcn_mfma_f32_16x16x32_f16(ONESH, BB, sB, 0, 0, 0);

        a00 = __builtin_amdgcn_mfma_f32_16x16x32_f16(A0c, BA, a00, 0, 0, 0);
        a01 = __builtin_amdgcn_mfma_f32_16x16x32_f16(A0c, BB, a01, 0, 0, 0);
        a10 = __builtin_amdgcn_mfma_f32_16x16x32_f16(A1c, BA, a10, 0, 0, 0);
        a11 = __builtin_amdgcn_mfma_f32_16x16x32_f16(A1c, BB, a11, 0, 0, 0);
        a20 = __builtin_amdgcn_mfma_f32_16x16x32_f16(A2c, BA, a20, 0, 0, 0);
        a21 = __builtin_amdgcn_mfma_f32_16x16x32_f16(A2c, BB, a21, 0, 0, 0);
        a30 = __builtin_amdgcn_mfma_f32_16x16x32_f16(A3c, BA, a30, 0, 0, 0);
        a31 = __builtin_amdgcn_mfma_f32_16x16x32_f16(A3c, BB, a31, 0, 0, 0);
        __builtin_amdgcn_s_setprio(0);

        epc = epn; enc = enn;
        bAc = bAn; bBc = bBn;
    }
#undef SPAIR

    // ---- merged epilogue: block-wide reduce over the 16 j-chunk waves ----
    float* rw = red + (size_t)(w * 64 + l) * RSTRIDE;
    *(float4*)(rw + 0)  = *(float4*)&a00;
    *(float4*)(rw + 4)  = *(float4*)&a01;
    *(float4*)(rw + 8)  = *(float4*)&a10;
    *(float4*)(rw + 12) = *(float4*)&a11;
    *(float4*)(rw + 16) = *(float4*)&a20;
    *(float4*)(rw + 20) = *(float4*)&a21;
    *(float4*)(rw + 24) = *(float4*)&a30;
    *(float4*)(rw + 28) = *(float4*)&a31;
    if (l < 16) {
        redl[w * 32 + il]      = sA[0];
        redl[w * 32 + 16 + il] = sB[0];
    }
    __syncthreads();

    const int row = tid >> 5;            // 0..31
    const int n0  = (tid & 31) * 2;      // 0,2,...,62
    const int h   = row >> 4;
    const int il2 = row & 15;

    float den = 0.f;
    #pragma unroll
    for (int w2 = 0; w2 < 16; ++w2) den += redl[w2 * 32 + row];
    const float inv = 1.0f / den;

    float o2[2];
    #pragma unroll
    for (int e = 0; e < 2; ++e) {
        const int n   = n0 + e;
        const int q   = n >> 4;
        const int kg2 = (n >> 2) & 3;
        const int r   = n & 3;
        float s = 0.f;
        #pragma unroll
        for (int w2 = 0; w2 < 16; ++w2)
            s += red[(size_t)(w2 * 64 + kg2 * 16 + il2) * RSTRIDE + q * 8 + h * 4 + r];
        o2[e] = s * inv;
    }
    *(float2*)&out[(size_t)(i0 + row) * OUTF + n0] = *(float2*)o2;
}

extern "C" void kernel_launch(void* const* d_in, const int* in_sizes, int n_in,
                              void* d_out, int out_size, void* d_ws, size_t ws_size,
                              hipStream_t stream) {
    const float* x   = (const float*)d_in[0];
    const int*   adj = (const int*)d_in[1];
    const float* W   = (const float*)d_in[2];
    const float* a   = (const float*)d_in[3];
    float* out = (float*)d_out;

    char* ws = (char*)d_ws;
    unsigned short* Asw = (unsigned short*)ws;                        // 1 MB
    float* U     = (float*)(ws + (1 << 20));                          // 32 KB
    unsigned short* e2ph = (unsigned short*)(ws + (1 << 20) + 32768); // 16 KB
    unsigned short* e2nh = (unsigned short*)(ws + (1 << 20) + 49152); // 16 KB
    unsigned* mask = (unsigned*)(ws + (1 << 20) + 65536);             // 8 MB

    k01_fused<<<GEMM_BLOCKS + NN, 256, 0, stream>>>(x, adj, W, a, Asw,
                                                    U, e2ph, e2nh, mask);
    k2_final<<<NN / 32, 1024, 0, stream>>>(mask, Asw, U, e2ph, e2nh, out);
}